// Round 10
// baseline (927.684 us; speedup 1.0000x reference)
//
#include <hip/hip_runtime.h>

#define NND 10000
#define NE  320000
#define DD  128
#define NDEPTH 4
#define TE  64   // edges per tile in edge kernel
#define GN  4    // nodes owned per edge-block (atomic-free aggregation)

typedef __attribute__((ext_vector_type(8))) short s8b;
typedef __attribute__((ext_vector_type(4))) float f4;
typedef unsigned short u16;
typedef unsigned int   u32;

__device__ __forceinline__ u16 f2b(float f) {
    u32 u = __builtin_bit_cast(u32, f);
    u32 r = (u + 0x7fffu + ((u >> 16) & 1u)) >> 16;   // RNE, finite inputs
    return (u16)r;
}

__device__ __forceinline__ float b2f(u16 b) {
    u32 u = (u32)b << 16;
    return __builtin_bit_cast(float, u);
}

__device__ __forceinline__ void bpair(u32 v, float& lo, float& hi) {
    lo = __builtin_bit_cast(float, v << 16);
    hi = __builtin_bit_cast(float, v & 0xffff0000u);
}

// packed RNE f32x2 -> bf16x2 (lo = first arg)
__device__ __forceinline__ u32 cvt_pk(float lo, float hi) {
    u32 r;
    asm("v_cvt_pk_bf16_f32 %0, %1, %2" : "=v"(r) : "v"(lo), "v"(hi));
    return r;
}

// single f32 -> bf16 via HW cvt
__device__ __forceinline__ u16 f2b1(float v) {
    return (u16)cvt_pk(v, v);
}

// fast silu: v * rcp(1+exp(-v)); bf16-rounded downstream, rcp's ~1ulp invisible
__device__ __forceinline__ float silu_f(float v) {
    return v * __builtin_amdgcn_rcpf(1.0f + __expf(-v));
}

// A-fragment for mfma_f32_16x16x32_bf16: lane holds k = k0 + {4g..4g+3, 16+4g..16+4g+3}
__device__ __forceinline__ s8b frag_a(const u16* rowp, int g) {
    union { s8b v; uint2 u2[2]; } r;
    r.u2[0] = *(const uint2*)(rowp + 4 * g);
    r.u2[1] = *(const uint2*)(rowp + 16 + 4 * g);
    return r.v;
}

__device__ __forceinline__ f4 mfma16(s8b a, s8b b, f4 c) {
    return __builtin_amdgcn_mfma_f32_16x16x32_bf16(a, b, c, 0, 0, 0);
}

// ---------------- weight packing: B-fragment layout, bf16 ----------------
__global__ __launch_bounds__(256) void egnn_pack(
    const float* __restrict__ ew1, const float* __restrict__ ew2,
    const float* __restrict__ nw1, const float* __restrict__ nw2,
    const float* __restrict__ cw1, u16* __restrict__ pw)
{
    int t = blockIdx.x * 256 + threadIdx.x;
    if (t >= 25 * 16384) return;
    int mat = t >> 14;
    int r   = t & 16383;
    int kt  = r >> 12;
    int nt  = (r >> 9) & 7;
    int lane= (r >> 3) & 63;
    int j   = r & 7;
    int g = lane >> 4, l15 = lane & 15;
    int k = kt * 32 + ((j < 4) ? (4 * g + j) : (16 + 4 * g + (j - 4)));
    int n = nt * 16 + l15;
    float v;
    if (mat < 24) {
        int layer = mat / 6, tp = mat % 6;
        switch (tp) {
            case 0: v = ew1[((size_t)layer * 257 + k) * DD + n]; break;
            case 1: v = ew1[((size_t)layer * 257 + 128 + k) * DD + n]; break;
            case 2: v = ew2[((size_t)layer * 128 + k) * DD + n]; break;
            case 3: v = nw1[((size_t)layer * 256 + k) * DD + n]; break;
            case 4: v = nw1[((size_t)layer * 256 + 128 + k) * DD + n]; break;
            default: v = nw2[((size_t)layer * 128 + k) * DD + n]; break;
        }
    } else {
        v = cw1[(size_t)k * DD + n];
    }
    pw[t] = f2b(v);
}

// ---------------- h init: bf16 copy ----------------
__global__ __launch_bounds__(256) void egnn_init(
    const float* __restrict__ h, u16* __restrict__ hb)
{
    int i = blockIdx.x * 256 + threadIdx.x;
    size_t base = (size_t)i * 4;
    if (base >= (size_t)NND * DD) return;
    float4 v = *(const float4*)(h + base);
    union { u16 s[4]; uint2 u; } t2;
    t2.s[0] = f2b(v.x); t2.s[1] = f2b(v.y); t2.s[2] = f2b(v.z); t2.s[3] = f2b(v.w);
    *(uint2*)(hb + base) = t2.u;
}

// ---------------- counting sort by row ----------------
__global__ __launch_bounds__(256) void egnn_count(
    const int* __restrict__ edges, int* __restrict__ cnts)
{
    int e = blockIdx.x * 256 + threadIdx.x;
    if (e < NE) atomicAdd(&cnts[edges[e]], 1);
}

__global__ __launch_bounds__(1024) void egnn_scan(
    const int* __restrict__ cnts, int* __restrict__ off, int* __restrict__ cursor)
{
    __shared__ int part[1024];
    const int t = threadIdx.x;
    const int base = t * 10;
    int s = 0;
    #pragma unroll
    for (int j = 0; j < 10; ++j) {
        int i = base + j;
        s += (i < NND) ? cnts[i] : 0;
    }
    part[t] = s;
    __syncthreads();
    for (int d = 1; d < 1024; d <<= 1) {
        int v = (t >= d) ? part[t - d] : 0;
        __syncthreads();
        part[t] += v;
        __syncthreads();
    }
    int run = (t == 0) ? 0 : part[t - 1];
    #pragma unroll
    for (int j = 0; j < 10; ++j) {
        int i = base + j;
        if (i <= NND) { off[i] = run; cursor[i] = run; }
        if (i < NND) run += cnts[i];
    }
}

// writes row-sorted (rows, cols) pair
__global__ __launch_bounds__(256) void egnn_scatter(
    const int* __restrict__ edges, int* __restrict__ cursor,
    int* __restrict__ rows, int* __restrict__ cols)
{
    int e = blockIdx.x * 256 + threadIdx.x;
    if (e >= NE) return;
    int r = edges[e];
    int p = atomicAdd(&cursor[r], 1);
    rows[p] = r;
    cols[p] = edges[NE + e];
}

// ---------------- layer-0 P/Q precompute: P=h@W1a+b1 (f32), Q=h@W1b (bf16) ----------------
__global__ __launch_bounds__(256) void egnn_pre0(
    const u16* __restrict__ hb, const u16* __restrict__ pw,
    const float* __restrict__ eb1,
    float* __restrict__ Pb, u16* __restrict__ Qb)
{
    __shared__ __attribute__((aligned(16))) u16 tH[64][136];
    const int tid = threadIdx.x;
    const int n0  = blockIdx.x * 64;

    #pragma unroll
    for (int it = 0; it < 4; ++it) {
        int idx = tid + it * 256;            // 0..1023
        int el = idx >> 4, part = idx & 15;
        int node = n0 + el;
        if (node < NND) {
            *(uint4*)&tH[el][part * 8] = *(const uint4*)(hb + (size_t)node * DD + part * 8);
        } else {
            uint4 z = {0u, 0u, 0u, 0u};
            *(uint4*)&tH[el][part * 8] = z;
        }
    }
    __syncthreads();

    const int wv = tid >> 6, lane = tid & 63;
    const int g = lane >> 4, l15 = lane & 15;
    const int wrow = wv * 16;

    f4 accP[8], accQ[8];
    #pragma unroll
    for (int nt = 0; nt < 8; ++nt) { accP[nt] = f4{0.f,0.f,0.f,0.f}; accQ[nt] = f4{0.f,0.f,0.f,0.f}; }
    const u16* pwa = pw;            // layer 0 mat 0 (W1a)
    const u16* pwb = pw + 16384;    // layer 0 mat 1 (W1b)
    #pragma unroll
    for (int kt = 0; kt < 4; ++kt) {
        s8b a = frag_a(&tH[wrow + l15][kt * 32], g);
        const u16* ba = pwa + (size_t)kt * 4096 + lane * 8;
        const u16* bb = pwb + (size_t)kt * 4096 + lane * 8;
        #pragma unroll
        for (int nt = 0; nt < 8; ++nt) {
            accP[nt] = mfma16(a, *(const s8b*)(ba + nt * 512), accP[nt]);
            accQ[nt] = mfma16(a, *(const s8b*)(bb + nt * 512), accQ[nt]);
        }
    }
    #pragma unroll
    for (int nt = 0; nt < 8; ++nt) {
        int n = nt * 16 + l15;
        float bb = eb1[n];      // layer 0 bias folded into P
        #pragma unroll
        for (int r = 0; r < 4; ++r) {
            int node = n0 + wrow + g * 4 + r;
            if (node < NND) {
                Pb[(size_t)node * DD + n] = accP[nt][r] + bb;
                Qb[(size_t)node * DD + n] = f2b1(accQ[nt][r]);
            }
        }
    }
}

// ---------------- edge kernel: node-ownership blocks, ZERO global atomics ----------------
// Block b owns nodes [4b,4b+4) and all their sorted edges [off[4b],off[4b+4)) (~128, tiles of 64).
// magg accumulated in LDS maccL across tiles, stored once as plain bf16 (2.56MB total vs 76MB
// atomic churn). Coord agg likewise in LDS aggL -> one plain store. P for the 4 owned nodes
// preloaded to LDS (2KB). Q gather stays bf16/L2-resident.
__global__ __launch_bounds__(256, 6) void egnn_edge(
    const float* __restrict__ Pb, const u16* __restrict__ Qb,
    const float* __restrict__ xin,
    const int* __restrict__ rows, const int* __restrict__ cols,
    const int* __restrict__ off,
    const u16* __restrict__ pw,
    const float* __restrict__ ew1,
    const float* __restrict__ eb2, const float* __restrict__ cb1,
    const float* __restrict__ cw2,
    u16* __restrict__ maggb, float* __restrict__ aggx,
    int layer, int last)
{
    __shared__ __attribute__((aligned(16))) u16 tA[TE][136];   // m1 then m2 per tile
    __shared__ __attribute__((aligned(16))) float Pg[GN][DD];  // owned-node P rows
    __shared__ float wrL[DD];
    __shared__ float maccL[GN][DD];
    __shared__ float aggL[GN][3];
    __shared__ float rad[TE];
    __shared__ float cdf[TE][3];
    __shared__ int   ridx[TE];
    __shared__ int   cidx[TE];
    __shared__ unsigned char segflag[TE];

    const int tid  = threadIdx.x;
    const int base = blockIdx.x * GN;
    const int e0 = off[base], e1 = off[base + GN];

    // preload P rows of owned nodes (contiguous, coalesced) + w1r; zero accumulators
    ((float2*)&Pg[0][0])[tid] = ((const float2*)(Pb + (size_t)base * DD))[tid];
    if (tid < 64)
        ((float2*)wrL)[tid] = ((const float2*)(ew1 + ((size_t)layer * 257 + 256) * DD))[tid];
    ((float2*)&maccL[0][0])[tid] = float2{0.f, 0.f};
    if (tid < GN * 3) ((float*)aggL)[tid] = 0.f;

    const int wv = tid >> 6, lane = tid & 63;
    const int g = lane >> 4, l15 = lane & 15;
    const int wrow = wv * 16;
    const int cg = tid & 15, rg = tid >> 4;
    const u16* pw2 = pw + (size_t)(layer * 6 + 2) * 16384;
    const u16* pwc = pw + (size_t)24 * 16384;
    const float* b2p = eb2 + (size_t)layer * DD;

    for (int t0 = e0; t0 < e1; t0 += TE) {
        const int nv = min(TE, e1 - t0);
        __syncthreads();                      // tA / index arrays free to overwrite
        if (tid < TE) {
            int p = t0 + (tid < nv ? tid : 0);   // pads alias edge 0 (safe indices)
            int r = rows[p], c = cols[p];
            ridx[tid] = r; cidx[tid] = c;
            float d0 = xin[r * 3 + 0] - xin[c * 3 + 0];
            float d1 = xin[r * 3 + 1] - xin[c * 3 + 1];
            float d2 = xin[r * 3 + 2] - xin[c * 3 + 2];
            rad[tid] = d0 * d0 + d1 * d1 + d2 * d2;
            cdf[tid][0] = d0; cdf[tid][1] = d1; cdf[tid][2] = d2;
        }
        __syncthreads();
        if (tid < TE)
            segflag[tid] = (tid == 0) || (ridx[tid] != ridx[tid - 1]);

        // ---- m1 staging: silu(Pg[ln] + Q[col] + rad*w1r) -> tA (bf16)
        {
            float4 w0 = *(const float4*)&wrL[cg * 8];
            float4 w4 = *(const float4*)&wrL[cg * 8 + 4];
            #pragma unroll
            for (int k = 0; k < 4; ++k) {
                int row = rg + 16 * k;
                int ln = ridx[row] - base;     // 0..GN-1
                float rd = rad[row];
                int cn = cidx[row];
                float4 pa = *(const float4*)&Pg[ln][cg * 8];
                float4 pc = *(const float4*)&Pg[ln][cg * 8 + 4];
                uint4 qv = *(const uint4*)(Qb + (size_t)cn * DD + cg * 8);
                float q0, q1, q2, q3, q4, q5, q6, q7;
                bpair(qv.x, q0, q1);
                bpair(qv.y, q2, q3);
                bpair(qv.z, q4, q5);
                bpair(qv.w, q6, q7);
                float v0 = silu_f(pa.x + q0 + rd * w0.x);
                float v1 = silu_f(pa.y + q1 + rd * w0.y);
                float v2 = silu_f(pa.z + q2 + rd * w0.z);
                float v3 = silu_f(pa.w + q3 + rd * w0.w);
                float v4 = silu_f(pc.x + q4 + rd * w4.x);
                float v5 = silu_f(pc.y + q5 + rd * w4.y);
                float v6 = silu_f(pc.z + q6 + rd * w4.z);
                float v7 = silu_f(pc.w + q7 + rd * w4.w);
                union { u32 w[4]; uint4 u; } cv;
                cv.w[0] = cvt_pk(v0, v1);
                cv.w[1] = cvt_pk(v2, v3);
                cv.w[2] = cvt_pk(v4, v5);
                cv.w[3] = cvt_pk(v6, v7);
                *(uint4*)&tA[row][cg * 8] = cv.u;
            }
        }
        __syncthreads();

        // ---- GEMM2: m1 (K=128) @ W2, 16 rows per wave
        f4 acc2[8];
        #pragma unroll
        for (int nt = 0; nt < 8; ++nt) acc2[nt] = f4{0.f, 0.f, 0.f, 0.f};
        #pragma unroll
        for (int kt = 0; kt < 4; ++kt) {
            s8b a = frag_a(&tA[wrow + l15][kt * 32], g);
            const u16* pb = pw2 + (size_t)kt * 4096 + lane * 8;
            #pragma unroll
            for (int nt = 0; nt < 8; ++nt) {
                s8b b = *(const s8b*)(pb + nt * 512);
                acc2[nt] = mfma16(a, b, acc2[nt]);
            }
        }
        // epilogue: m2 = silu(acc2 + b2) -> tA in place (wave-private rows)
        #pragma unroll
        for (int nt = 0; nt < 8; ++nt) {
            int n = nt * 16 + l15;
            float bb = b2p[n];
            #pragma unroll
            for (int r = 0; r < 4; ++r) {
                int er = wrow + g * 4 + r;
                tA[er][n] = f2b1(silu_f(acc2[nt][r] + bb));
            }
        }
        __syncthreads();

        // ---- segmented reduce -> maccL (LDS, col-owner threads, no races)
        if (tid < 128) {
            int col = tid;
            float s = 0.f;
            for (int row = 0; row < nv; ++row) {
                s += b2f(tA[row][col]);
                if (row == nv - 1 || segflag[row + 1]) {
                    maccL[ridx[row] - base][col] += s;
                    s = 0.f;
                }
            }
        }

        if (last) {
            // ---- coord GEMM: m2 (K=128) @ Wc1 ; dot cw2 ; accumulate trans in aggL
            f4 acc3[8];
            #pragma unroll
            for (int nt = 0; nt < 8; ++nt) acc3[nt] = f4{0.f, 0.f, 0.f, 0.f};
            #pragma unroll
            for (int kt = 0; kt < 4; ++kt) {
                s8b a = frag_a(&tA[wrow + l15][kt * 32], g);
                const u16* pb = pwc + (size_t)kt * 4096 + lane * 8;
                #pragma unroll
                for (int nt = 0; nt < 8; ++nt) {
                    s8b b = *(const s8b*)(pb + nt * 512);
                    acc3[nt] = mfma16(a, b, acc3[nt]);
                }
            }
            float p[4];
            #pragma unroll
            for (int r = 0; r < 4; ++r) p[r] = 0.f;
            #pragma unroll
            for (int nt = 0; nt < 8; ++nt) {
                int n = nt * 16 + l15;
                float bb = cb1[n], w2 = cw2[n];
                #pragma unroll
                for (int r = 0; r < 4; ++r)
                    p[r] += silu_f(acc3[nt][r] + bb) * w2;
            }
            #pragma unroll
            for (int o = 1; o < 16; o <<= 1) {
                #pragma unroll
                for (int r = 0; r < 4; ++r)
                    p[r] += __shfl_xor(p[r], o);
            }
            if (l15 == 0) {
                #pragma unroll
                for (int r = 0; r < 4; ++r) {
                    int er = wrow + 4 * g + r;
                    if (er < nv) {
                        int ln = ridx[er] - base;
                        float w = p[r];
                        atomicAdd(&aggL[ln][0], cdf[er][0] * w);
                        atomicAdd(&aggL[ln][1], cdf[er][1] * w);
                        atomicAdd(&aggL[ln][2], cdf[er][2] * w);
                    }
                }
            }
        }
    }
    __syncthreads();

    // ---- final plain stores: maccL -> maggb (bf16), aggL -> aggx
    {
        int l = tid >> 6, cp = tid & 63;       // 4 nodes x 64 u32 (128 cols)
        u32 w = cvt_pk(maccL[l][cp * 2], maccL[l][cp * 2 + 1]);
        *(u32*)(maggb + (size_t)(base + l) * DD + cp * 2) = w;
    }
    if (last && tid < GN * 3) {
        aggx[base * 3 + tid] = ((const float*)aggL)[tid];
    }
}

// ---------------- node kernel (+ fused next-layer P/Q precompute) ----------------
__global__ __launch_bounds__(256) void egnn_node(
    const u16* __restrict__ hb, const float* __restrict__ resid,
    const u16* __restrict__ maggb, const u16* __restrict__ pw,
    const float* __restrict__ nb1, const float* __restrict__ nb2,
    const float* __restrict__ eb1,
    float* __restrict__ out_h, u16* __restrict__ hb_out,
    float* __restrict__ Pb, u16* __restrict__ Qb,
    int layer, int last)
{
    __shared__ __attribute__((aligned(16))) u16 tH[64][136];
    __shared__ __attribute__((aligned(16))) u16 tM[64][136];
    const int tid = threadIdx.x;
    const int n0  = blockIdx.x * 64;

    #pragma unroll
    for (int it = 0; it < 4; ++it) {
        int idx = tid + it * 256;            // 0..1023
        int el = idx >> 4, part = idx & 15;
        int node = n0 + el;
        if (node < NND) {
            *(uint4*)&tH[el][part * 8] = *(const uint4*)(hb + (size_t)node * DD + part * 8);
            *(uint4*)&tM[el][part * 8] = *(const uint4*)(maggb + (size_t)node * DD + part * 8);
        } else {
            uint4 z = {0u, 0u, 0u, 0u};
            *(uint4*)&tH[el][part * 8] = z;
            *(uint4*)&tM[el][part * 8] = z;
        }
    }
    __syncthreads();

    const int wv = tid >> 6, lane = tid & 63;
    const int g = lane >> 4, l15 = lane & 15;
    const int wrow = wv * 16;

    f4 acc[8];
    #pragma unroll
    for (int nt = 0; nt < 8; ++nt) acc[nt] = f4{0.f, 0.f, 0.f, 0.f};
    const u16* pn1a = pw + (size_t)(layer * 6 + 3) * 16384;
    const u16* pn1b = pw + (size_t)(layer * 6 + 4) * 16384;
    #pragma unroll
    for (int kt = 0; kt < 8; ++kt) {
        const u16 (*tile)[136] = (kt < 4) ? tH : tM;
        const int k0 = (kt & 3) * 32;
        s8b a = frag_a(&tile[wrow + l15][k0], g);
        const u16* pb = ((kt < 4) ? pn1a : pn1b) + (size_t)(kt & 3) * 4096 + lane * 8;
        #pragma unroll
        for (int nt = 0; nt < 8; ++nt) {
            s8b b = *(const s8b*)(pb + nt * 512);
            acc[nt] = mfma16(a, b, acc[nt]);
        }
    }
    {
        const float* b1 = nb1 + (size_t)layer * DD;
        #pragma unroll
        for (int nt = 0; nt < 8; ++nt) {
            int n = nt * 16 + l15;
            float bb = b1[n];
            #pragma unroll
            for (int r = 0; r < 4; ++r) {
                int er = wrow + g * 4 + r;
                tM[er][n] = f2b1(silu_f(acc[nt][r] + bb));
            }
        }
    }
    __syncthreads();

    f4 acc2[8];
    #pragma unroll
    for (int nt = 0; nt < 8; ++nt) acc2[nt] = f4{0.f, 0.f, 0.f, 0.f};
    const u16* pn2 = pw + (size_t)(layer * 6 + 5) * 16384;
    #pragma unroll
    for (int kt = 0; kt < 4; ++kt) {
        s8b a = frag_a(&tM[wrow + l15][kt * 32], g);
        const u16* pb = pn2 + (size_t)kt * 4096 + lane * 8;
        #pragma unroll
        for (int nt = 0; nt < 8; ++nt) {
            s8b b = *(const s8b*)(pb + nt * 512);
            acc2[nt] = mfma16(a, b, acc2[nt]);
        }
    }
    {
        const float* b2 = nb2 + (size_t)layer * DD;
        #pragma unroll
        for (int nt = 0; nt < 8; ++nt) {
            int n = nt * 16 + l15;
            float bb = b2[n];
            #pragma unroll
            for (int r = 0; r < 4; ++r) {
                int er = wrow + g * 4 + r;
                int node = n0 + er;
                if (node < NND) {
                    float v = acc2[nt][r] + bb + resid[(size_t)node * DD + n];
                    out_h[(size_t)node * DD + n] = v;
                    if (!last) {
                        u16 hv = f2b1(v);
                        hb_out[(size_t)node * DD + n] = hv;
                        tH[er][n] = hv;           // stage h_{l+1} for P/Q GEMM
                    }
                } else if (!last) {
                    tH[er][n] = 0;
                }
            }
        }
    }

    if (!last) {
        __syncthreads();
        // next-layer P = h@W1a + b1 (f32), Q = h@W1b (bf16)
        f4 accP[8], accQ[8];
        #pragma unroll
        for (int nt = 0; nt < 8; ++nt) { accP[nt] = f4{0.f,0.f,0.f,0.f}; accQ[nt] = f4{0.f,0.f,0.f,0.f}; }
        const u16* pwa = pw + (size_t)((layer + 1) * 6 + 0) * 16384;
        const u16* pwb = pw + (size_t)((layer + 1) * 6 + 1) * 16384;
        #pragma unroll
        for (int kt = 0; kt < 4; ++kt) {
            s8b a = frag_a(&tH[wrow + l15][kt * 32], g);
            const u16* ba = pwa + (size_t)kt * 4096 + lane * 8;
            const u16* bb = pwb + (size_t)kt * 4096 + lane * 8;
            #pragma unroll
            for (int nt = 0; nt < 8; ++nt) {
                accP[nt] = mfma16(a, *(const s8b*)(ba + nt * 512), accP[nt]);
                accQ[nt] = mfma16(a, *(const s8b*)(bb + nt * 512), accQ[nt]);
            }
        }
        #pragma unroll
        for (int nt = 0; nt < 8; ++nt) {
            int n = nt * 16 + l15;
            float bb = eb1[(size_t)(layer + 1) * DD + n];
            #pragma unroll
            for (int r = 0; r < 4; ++r) {
                int node = n0 + wrow + g * 4 + r;
                if (node < NND) {
                    Pb[(size_t)node * DD + n] = accP[nt][r] + bb;
                    Qb[(size_t)node * DD + n] = f2b1(accQ[nt][r]);
                }
            }
        }
    }
}

// ---------------- final coord output ----------------
__global__ __launch_bounds__(256) void egnn_coord_out(
    const float* __restrict__ xin, const float* __restrict__ aggx,
    const int* __restrict__ off, float* __restrict__ out_x)
{
    int i = blockIdx.x * 256 + threadIdx.x;
    if (i >= NND) return;
    float c = (float)(off[i + 1] - off[i]);
    float inv = 1.0f / fmaxf(c, 1.0f);
    out_x[i * 3 + 0] = xin[i * 3 + 0] + aggx[i * 3 + 0] * inv;
    out_x[i * 3 + 1] = xin[i * 3 + 1] + aggx[i * 3 + 1] * inv;
    out_x[i * 3 + 2] = xin[i * 3 + 2] + aggx[i * 3 + 2] * inv;
}

extern "C" void kernel_launch(void* const* d_in, const int* in_sizes, int n_in,
                              void* d_out, int out_size, void* d_ws, size_t ws_size,
                              hipStream_t stream) {
    const float* h   = (const float*)d_in[0];
    const float* x   = (const float*)d_in[1];
    const int*  edges= (const int*)d_in[2];
    const float* ew1 = (const float*)d_in[3];
    const float* eb1 = (const float*)d_in[4];
    const float* ew2 = (const float*)d_in[5];
    const float* eb2 = (const float*)d_in[6];
    const float* nw1 = (const float*)d_in[7];
    const float* nb1 = (const float*)d_in[8];
    const float* nw2 = (const float*)d_in[9];
    const float* nb2 = (const float*)d_in[10];
    const float* cw1 = (const float*)d_in[11];
    const float* cb1 = (const float*)d_in[12];
    const float* cw2 = (const float*)d_in[13];

    char* ws = (char*)d_ws;
    u16*   hb   = (u16*)  (ws);                    //  2,560,000
    u16*   pw   = (u16*)  (ws + 2560000);          //    819,200
    int*   cnts = (int*)  (ws + 3379200);          //     40,016
    int*   off  = (int*)  (ws + 3419216);          //     40,016
    int*   curs = (int*)  (ws + 3459232);          //     40,016
    int*   rows = (int*)  (ws + 3499248);          //  1,280,000
    int*   cols = (int*)  (ws + 4779248);          //  1,280,000
    float* aggx = (float*)(ws + 6059248);          //    120,064
    float* Pb   = (float*)(ws + 6179312);          //  5,120,000
    u16*   Qb   = (u16*)  (ws + 11299312);         //  2,560,000
    u16*   maggb= (u16*)  (ws + 13859312);         //  2,560,000  (total 16,419,312)

    float* out_h = (float*)d_out;
    float* out_x = out_h + (size_t)NND * DD;

    egnn_pack<<<1600, 256, 0, stream>>>(ew1, ew2, nw1, nw2, cw1, pw);
    egnn_init<<<1250, 256, 0, stream>>>(h, hb);
    hipMemsetAsync(cnts, 0, 40016, stream);

    egnn_count<<<1250, 256, 0, stream>>>(edges, cnts);
    egnn_scan<<<1, 1024, 0, stream>>>(cnts, off, curs);
    egnn_scatter<<<1250, 256, 0, stream>>>(edges, curs, rows, cols);
    egnn_pre0<<<(NND + 63) / 64, 256, 0, stream>>>(hb, pw, eb1, Pb, Qb);

    for (int i = 0; i < NDEPTH; ++i) {
        int last = (i == NDEPTH - 1);
        egnn_edge<<<NND / GN, 256, 0, stream>>>(Pb, Qb, x, rows, cols, off, pw,
                                                ew1, eb2, cb1, cw2,
                                                maggb, aggx, i, last);
        const float* resid = (i == 0) ? h : (const float*)out_h;
        egnn_node<<<(NND + 63) / 64, 256, 0, stream>>>(hb, resid, maggb, pw, nb1, nb2, eb1,
                                                       out_h, hb, Pb, Qb, i, last);
    }
    egnn_coord_out<<<40, 256, 0, stream>>>(x, aggx, off, out_x);
}

// Round 11
// 510.790 us; speedup vs baseline: 1.8162x; 1.8162x over previous
//
#include <hip/hip_runtime.h>

#define NND 10000
#define NE  320000
#define DD  128
#define NDEPTH 4
#define TE  64   // edges per block in edge kernel (256 threads, 4 waves, 16 rows/wave)

typedef __attribute__((ext_vector_type(8))) short s8b;
typedef __attribute__((ext_vector_type(4))) float f4;
typedef unsigned short u16;
typedef unsigned int   u32;

__device__ __forceinline__ u16 f2b(float f) {
    u32 u = __builtin_bit_cast(u32, f);
    u32 r = (u + 0x7fffu + ((u >> 16) & 1u)) >> 16;   // RNE, finite inputs
    return (u16)r;
}

__device__ __forceinline__ float b2f(u16 b) {
    u32 u = (u32)b << 16;
    return __builtin_bit_cast(float, u);
}

__device__ __forceinline__ void bpair(u32 v, float& lo, float& hi) {
    lo = __builtin_bit_cast(float, v << 16);
    hi = __builtin_bit_cast(float, v & 0xffff0000u);
}

// packed RNE f32x2 -> bf16x2 (lo = first arg)
__device__ __forceinline__ u32 cvt_pk(float lo, float hi) {
    u32 r;
    asm("v_cvt_pk_bf16_f32 %0, %1, %2" : "=v"(r) : "v"(lo), "v"(hi));
    return r;
}

// single f32 -> bf16 via HW cvt (1 instruction vs 5-op manual RNE)
__device__ __forceinline__ u16 f2b1(float v) {
    return (u16)cvt_pk(v, v);
}

// fast silu: v * rcp(1+exp(-v)); output always rounds to bf16 downstream,
// so v_rcp_f32's ~1ulp is invisible.
__device__ __forceinline__ float silu_f(float v) {
    return v * __builtin_amdgcn_rcpf(1.0f + __expf(-v));
}

// A-fragment for mfma_f32_16x16x32_bf16: lane holds k = k0 + {4g..4g+3, 16+4g..16+4g+3}
__device__ __forceinline__ s8b frag_a(const u16* rowp, int g) {
    union { s8b v; uint2 u2[2]; } r;
    r.u2[0] = *(const uint2*)(rowp + 4 * g);
    r.u2[1] = *(const uint2*)(rowp + 16 + 4 * g);
    return r.v;
}

__device__ __forceinline__ f4 mfma16(s8b a, s8b b, f4 c) {
    return __builtin_amdgcn_mfma_f32_16x16x32_bf16(a, b, c, 0, 0, 0);
}

// ---------------- weight packing: B-fragment layout, bf16 ----------------
__global__ __launch_bounds__(256) void egnn_pack(
    const float* __restrict__ ew1, const float* __restrict__ ew2,
    const float* __restrict__ nw1, const float* __restrict__ nw2,
    const float* __restrict__ cw1, u16* __restrict__ pw)
{
    int t = blockIdx.x * 256 + threadIdx.x;
    if (t >= 25 * 16384) return;
    int mat = t >> 14;
    int r   = t & 16383;
    int kt  = r >> 12;
    int nt  = (r >> 9) & 7;
    int lane= (r >> 3) & 63;
    int j   = r & 7;
    int g = lane >> 4, l15 = lane & 15;
    int k = kt * 32 + ((j < 4) ? (4 * g + j) : (16 + 4 * g + (j - 4)));
    int n = nt * 16 + l15;
    float v;
    if (mat < 24) {
        int layer = mat / 6, tp = mat % 6;
        switch (tp) {
            case 0: v = ew1[((size_t)layer * 257 + k) * DD + n]; break;
            case 1: v = ew1[((size_t)layer * 257 + 128 + k) * DD + n]; break;
            case 2: v = ew2[((size_t)layer * 128 + k) * DD + n]; break;
            case 3: v = nw1[((size_t)layer * 256 + k) * DD + n]; break;
            case 4: v = nw1[((size_t)layer * 256 + 128 + k) * DD + n]; break;
            default: v = nw2[((size_t)layer * 128 + k) * DD + n]; break;
        }
    } else {
        v = cw1[(size_t)k * DD + n];
    }
    pw[t] = f2b(v);
}

// ---------------- h init: bf16 copy ----------------
__global__ __launch_bounds__(256) void egnn_init(
    const float* __restrict__ h, u16* __restrict__ hb)
{
    int i = blockIdx.x * 256 + threadIdx.x;
    size_t base = (size_t)i * 4;
    if (base >= (size_t)NND * DD) return;
    float4 v = *(const float4*)(h + base);
    union { u16 s[4]; uint2 u; } t2;
    t2.s[0] = f2b(v.x); t2.s[1] = f2b(v.y); t2.s[2] = f2b(v.z); t2.s[3] = f2b(v.w);
    *(uint2*)(hb + base) = t2.u;
}

// ---------------- counting sort by row ----------------
__global__ __launch_bounds__(256) void egnn_count(
    const int* __restrict__ edges, int* __restrict__ cnts)
{
    int e = blockIdx.x * 256 + threadIdx.x;
    if (e < NE) atomicAdd(&cnts[edges[e]], 1);
}

__global__ __launch_bounds__(1024) void egnn_scan(
    const int* __restrict__ cnts, int* __restrict__ off, int* __restrict__ cursor)
{
    __shared__ int part[1024];
    const int t = threadIdx.x;
    const int base = t * 10;
    int s = 0;
    #pragma unroll
    for (int j = 0; j < 10; ++j) {
        int i = base + j;
        s += (i < NND) ? cnts[i] : 0;
    }
    part[t] = s;
    __syncthreads();
    for (int d = 1; d < 1024; d <<= 1) {
        int v = (t >= d) ? part[t - d] : 0;
        __syncthreads();
        part[t] += v;
        __syncthreads();
    }
    int run = (t == 0) ? 0 : part[t - 1];
    #pragma unroll
    for (int j = 0; j < 10; ++j) {
        int i = base + j;
        if (i <= NND) { off[i] = run; cursor[i] = run; }
        if (i < NND) run += cnts[i];
    }
}

// writes row-sorted (rows, cols) pair; no perm indirection needed later
__global__ __launch_bounds__(256) void egnn_scatter(
    const int* __restrict__ edges, int* __restrict__ cursor,
    int* __restrict__ rows, int* __restrict__ cols)
{
    int e = blockIdx.x * 256 + threadIdx.x;
    if (e >= NE) return;
    int r = edges[e];
    int p = atomicAdd(&cursor[r], 1);
    rows[p] = r;
    cols[p] = edges[NE + e];
}

// ---------------- layer-0 P/Q precompute: P=h@W1a+b1 (f32), Q=h@W1b (bf16) ----------------
__global__ __launch_bounds__(256) void egnn_pre0(
    const u16* __restrict__ hb, const u16* __restrict__ pw,
    const float* __restrict__ eb1,
    float* __restrict__ Pb, u16* __restrict__ Qb)
{
    __shared__ __attribute__((aligned(16))) u16 tH[64][136];
    const int tid = threadIdx.x;
    const int n0  = blockIdx.x * 64;

    #pragma unroll
    for (int it = 0; it < 4; ++it) {
        int idx = tid + it * 256;            // 0..1023
        int el = idx >> 4, part = idx & 15;
        int node = n0 + el;
        if (node < NND) {
            *(uint4*)&tH[el][part * 8] = *(const uint4*)(hb + (size_t)node * DD + part * 8);
        } else {
            uint4 z = {0u, 0u, 0u, 0u};
            *(uint4*)&tH[el][part * 8] = z;
        }
    }
    __syncthreads();

    const int wv = tid >> 6, lane = tid & 63;
    const int g = lane >> 4, l15 = lane & 15;
    const int wrow = wv * 16;

    f4 accP[8], accQ[8];
    #pragma unroll
    for (int nt = 0; nt < 8; ++nt) { accP[nt] = f4{0.f,0.f,0.f,0.f}; accQ[nt] = f4{0.f,0.f,0.f,0.f}; }
    const u16* pwa = pw;            // layer 0 mat 0 (W1a)
    const u16* pwb = pw + 16384;    // layer 0 mat 1 (W1b)
    #pragma unroll
    for (int kt = 0; kt < 4; ++kt) {
        s8b a = frag_a(&tH[wrow + l15][kt * 32], g);
        const u16* ba = pwa + (size_t)kt * 4096 + lane * 8;
        const u16* bb = pwb + (size_t)kt * 4096 + lane * 8;
        #pragma unroll
        for (int nt = 0; nt < 8; ++nt) {
            accP[nt] = mfma16(a, *(const s8b*)(ba + nt * 512), accP[nt]);
            accQ[nt] = mfma16(a, *(const s8b*)(bb + nt * 512), accQ[nt]);
        }
    }
    #pragma unroll
    for (int nt = 0; nt < 8; ++nt) {
        int n = nt * 16 + l15;
        float bb = eb1[n];      // layer 0 bias folded into P
        #pragma unroll
        for (int r = 0; r < 4; ++r) {
            int node = n0 + wrow + g * 4 + r;
            if (node < NND) {
                Pb[(size_t)node * DD + n] = accP[nt][r] + bb;
                Qb[(size_t)node * DD + n] = f2b1(accQ[nt][r]);
            }
        }
    }
}

// ---------------- edge kernel (sorted edges, hybrid segmented reduce) ----------------
// TE=64, 4 waves, 16 GEMM rows/wave (acc[8]=32 AGPR -> high occupancy).
// Q stored bf16 (L2-resident). Reduce: single 64-row runs; segments whose node range
// lies ENTIRELY in this tile (detected via off[]) use plain stores over the memset
// zeros -- only tile-boundary nodes use atomicAdd (halves atomic churn).
__global__ __launch_bounds__(256, 6) void egnn_edge(
    const float* __restrict__ Pb, const u16* __restrict__ Qb,
    const float* __restrict__ xin,
    const int* __restrict__ rows, const int* __restrict__ cols,
    const int* __restrict__ off,
    const u16* __restrict__ pw,
    const float* __restrict__ ew1,
    const float* __restrict__ eb2, const float* __restrict__ cb1,
    const float* __restrict__ cw2,
    float* __restrict__ magg, float* __restrict__ aggx,
    int layer, int last)
{
    __shared__ __attribute__((aligned(16))) u16 tA[TE][136];  // m1 then m2 (in-place)
    __shared__ float rad[TE];
    __shared__ float cdf[TE][3];
    __shared__ int   ridx[TE];
    __shared__ int   cidx[TE];
    __shared__ unsigned char segflag[TE + 1];

    const int tid = threadIdx.x;
    // bijective XCD swizzle (grid 5000 % 8 == 0)
    const int nblk = NE / TE;
    const int bid  = blockIdx.x;
    const int blk  = (bid & 7) * (nblk >> 3) + (bid >> 3);
    const int p0   = blk * TE;

    if (tid < TE) {
        int p = p0 + tid;
        int r = rows[p];
        int c = cols[p];
        ridx[tid] = r; cidx[tid] = c;
        float d0 = xin[r * 3 + 0] - xin[c * 3 + 0];
        float d1 = xin[r * 3 + 1] - xin[c * 3 + 1];
        float d2 = xin[r * 3 + 2] - xin[c * 3 + 2];
        rad[tid] = d0 * d0 + d1 * d1 + d2 * d2;
        cdf[tid][0] = d0; cdf[tid][1] = d1; cdf[tid][2] = d2;
    }
    __syncthreads();

    if (tid < TE) {
        segflag[tid] = (tid == 0) || (ridx[tid] != ridx[tid - 1]);
        if (tid == 0) segflag[TE] = 1;
    }

    // ---- staging: m1 = silu(P'[row] + Q[col] + rad*w1r) -> tA (bf16)
    {
        const int cg = tid & 15;        // cols cg*8 .. cg*8+7
        const int rg = tid >> 4;        // 0..15, rows rg + 16*k
        const float* wrp = ew1 + ((size_t)layer * 257 + 256) * DD + cg * 8;
        float4 w0 = *(const float4*)(wrp);
        float4 w4 = *(const float4*)(wrp + 4);
        #pragma unroll
        for (int k = 0; k < 4; ++k) {
            int row = rg + 16 * k;
            int rn = ridx[row], cn = cidx[row];
            float rd = rad[row];
            const float* pp = Pb + (size_t)rn * DD + cg * 8;
            float4 pa = *(const float4*)(pp);
            float4 pc = *(const float4*)(pp + 4);
            uint4 qv = *(const uint4*)(Qb + (size_t)cn * DD + cg * 8);
            float q0, q1, q2, q3, q4, q5, q6, q7;
            bpair(qv.x, q0, q1);
            bpair(qv.y, q2, q3);
            bpair(qv.z, q4, q5);
            bpair(qv.w, q6, q7);
            float v0 = silu_f(pa.x + q0 + rd * w0.x);
            float v1 = silu_f(pa.y + q1 + rd * w0.y);
            float v2 = silu_f(pa.z + q2 + rd * w0.z);
            float v3 = silu_f(pa.w + q3 + rd * w0.w);
            float v4 = silu_f(pc.x + q4 + rd * w4.x);
            float v5 = silu_f(pc.y + q5 + rd * w4.y);
            float v6 = silu_f(pc.z + q6 + rd * w4.z);
            float v7 = silu_f(pc.w + q7 + rd * w4.w);
            union { u32 w[4]; uint4 u; } cv;
            cv.w[0] = cvt_pk(v0, v1);
            cv.w[1] = cvt_pk(v2, v3);
            cv.w[2] = cvt_pk(v4, v5);
            cv.w[3] = cvt_pk(v6, v7);
            *(uint4*)&tA[row][cg * 8] = cv.u;
        }
    }
    __syncthreads();

    const int wv = tid >> 6, lane = tid & 63;
    const int g = lane >> 4, l15 = lane & 15;
    const int wrow = wv * 16;

    // ---- GEMM2: m1 (K=128) @ W2, 16 rows per wave
    f4 acc2[8];
    #pragma unroll
    for (int nt = 0; nt < 8; ++nt) acc2[nt] = f4{0.f, 0.f, 0.f, 0.f};
    const u16* pw2 = pw + (size_t)(layer * 6 + 2) * 16384;
    #pragma unroll
    for (int kt = 0; kt < 4; ++kt) {
        s8b a = frag_a(&tA[wrow + l15][kt * 32], g);
        const u16* pb = pw2 + (size_t)kt * 4096 + lane * 8;
        #pragma unroll
        for (int nt = 0; nt < 8; ++nt) {
            s8b b = *(const s8b*)(pb + nt * 512);
            acc2[nt] = mfma16(a, b, acc2[nt]);
        }
    }
    // epilogue: m2 = silu(acc2 + b2) -> tA in place (wave-private rows)
    {
        const float* b2 = eb2 + (size_t)layer * DD;
        #pragma unroll
        for (int nt = 0; nt < 8; ++nt) {
            int n = nt * 16 + l15;
            float bb = b2[n];
            #pragma unroll
            for (int r = 0; r < 4; ++r) {
                int er = wrow + g * 4 + r;
                float v = silu_f(acc2[nt][r] + bb);
                tA[er][n] = f2b1(v);
            }
        }
    }
    __syncthreads();

    // ---- hybrid segmented reduce: complete segments -> plain store; else atomic
    if (tid < 128) {
        int col = tid;
        float s = 0.f;
        int sstart = 0;
        for (int row = 0; row < TE; ++row) {
            s += b2f(tA[row][col]);
            if (segflag[row + 1] || row == TE - 1) {
                int rn = ridx[row];
                // node's full edge range inside this tile? (wave-uniform branch)
                bool complete = (p0 + sstart == off[rn]) &&
                                (p0 + row == off[rn + 1] - 1);
                float* mg = &magg[(size_t)rn * DD + col];
                if (complete) *mg = s;
                else          atomicAdd(mg, s);
                s = 0.f;
                sstart = row + 1;
            }
        }
    }

    if (last) {
        // ---- coord GEMM: m2 (K=128) @ Wc1 ; dot with cw2 ; aggregate trans
        f4 acc3[8];
        #pragma unroll
        for (int nt = 0; nt < 8; ++nt) acc3[nt] = f4{0.f, 0.f, 0.f, 0.f};
        const u16* pwc = pw + (size_t)24 * 16384;
        #pragma unroll
        for (int kt = 0; kt < 4; ++kt) {
            s8b a = frag_a(&tA[wrow + l15][kt * 32], g);
            const u16* pb = pwc + (size_t)kt * 4096 + lane * 8;
            #pragma unroll
            for (int nt = 0; nt < 8; ++nt) {
                s8b b = *(const s8b*)(pb + nt * 512);
                acc3[nt] = mfma16(a, b, acc3[nt]);
            }
        }
        float p[4];
        #pragma unroll
        for (int r = 0; r < 4; ++r) p[r] = 0.f;
        #pragma unroll
        for (int nt = 0; nt < 8; ++nt) {
            int n = nt * 16 + l15;
            float bb = cb1[n], w2 = cw2[n];
            #pragma unroll
            for (int r = 0; r < 4; ++r)
                p[r] += silu_f(acc3[nt][r] + bb) * w2;
        }
        #pragma unroll
        for (int o = 1; o < 16; o <<= 1) {
            #pragma unroll
            for (int r = 0; r < 4; ++r)
                p[r] += __shfl_xor(p[r], o);
        }
        if (l15 == 0) {
            #pragma unroll
            for (int r = 0; r < 4; ++r) {
                int er = wrow + 4 * g + r;
                int rn2 = ridx[er];
                float w = p[r];
                atomicAdd(&aggx[rn2 * 3 + 0], cdf[er][0] * w);
                atomicAdd(&aggx[rn2 * 3 + 1], cdf[er][1] * w);
                atomicAdd(&aggx[rn2 * 3 + 2], cdf[er][2] * w);
            }
        }
    }
}

// ---------------- node kernel (+ fused next-layer P/Q precompute) ----------------
__global__ __launch_bounds__(256) void egnn_node(
    const u16* __restrict__ hb, const float* __restrict__ resid,
    const float* __restrict__ magg, const u16* __restrict__ pw,
    const float* __restrict__ nb1, const float* __restrict__ nb2,
    const float* __restrict__ eb1,
    float* __restrict__ out_h, u16* __restrict__ hb_out,
    float* __restrict__ Pb, u16* __restrict__ Qb,
    int layer, int last)
{
    __shared__ __attribute__((aligned(16))) u16 tH[64][136];
    __shared__ __attribute__((aligned(16))) u16 tM[64][136];
    const int tid = threadIdx.x;
    const int n0  = blockIdx.x * 64;

    #pragma unroll
    for (int it = 0; it < 4; ++it) {
        int idx = tid + it * 256;            // 0..1023
        int el = idx >> 4, part = idx & 15;
        int node = n0 + el;
        if (node < NND) {
            *(uint4*)&tH[el][part * 8] = *(const uint4*)(hb + (size_t)node * DD + part * 8);
            const float* ms = magg + (size_t)node * DD + part * 8;
            float4 m0 = *(const float4*)(ms);
            float4 m1 = *(const float4*)(ms + 4);
            union { u32 w[4]; uint4 u; } cv;
            cv.w[0] = cvt_pk(m0.x, m0.y);
            cv.w[1] = cvt_pk(m0.z, m0.w);
            cv.w[2] = cvt_pk(m1.x, m1.y);
            cv.w[3] = cvt_pk(m1.z, m1.w);
            *(uint4*)&tM[el][part * 8] = cv.u;
        } else {
            uint4 z = {0u, 0u, 0u, 0u};
            *(uint4*)&tH[el][part * 8] = z;
            *(uint4*)&tM[el][part * 8] = z;
        }
    }
    __syncthreads();

    const int wv = tid >> 6, lane = tid & 63;
    const int g = lane >> 4, l15 = lane & 15;
    const int wrow = wv * 16;

    f4 acc[8];
    #pragma unroll
    for (int nt = 0; nt < 8; ++nt) acc[nt] = f4{0.f, 0.f, 0.f, 0.f};
    const u16* pn1a = pw + (size_t)(layer * 6 + 3) * 16384;
    const u16* pn1b = pw + (size_t)(layer * 6 + 4) * 16384;
    #pragma unroll
    for (int kt = 0; kt < 8; ++kt) {
        const u16 (*tile)[136] = (kt < 4) ? tH : tM;
        const int k0 = (kt & 3) * 32;
        s8b a = frag_a(&tile[wrow + l15][k0], g);
        const u16* pb = ((kt < 4) ? pn1a : pn1b) + (size_t)(kt & 3) * 4096 + lane * 8;
        #pragma unroll
        for (int nt = 0; nt < 8; ++nt) {
            s8b b = *(const s8b*)(pb + nt * 512);
            acc[nt] = mfma16(a, b, acc[nt]);
        }
    }
    {
        const float* b1 = nb1 + (size_t)layer * DD;
        #pragma unroll
        for (int nt = 0; nt < 8; ++nt) {
            int n = nt * 16 + l15;
            float bb = b1[n];
            #pragma unroll
            for (int r = 0; r < 4; ++r) {
                int er = wrow + g * 4 + r;
                tM[er][n] = f2b1(silu_f(acc[nt][r] + bb));
            }
        }
    }
    __syncthreads();

    f4 acc2[8];
    #pragma unroll
    for (int nt = 0; nt < 8; ++nt) acc2[nt] = f4{0.f, 0.f, 0.f, 0.f};
    const u16* pn2 = pw + (size_t)(layer * 6 + 5) * 16384;
    #pragma unroll
    for (int kt = 0; kt < 4; ++kt) {
        s8b a = frag_a(&tM[wrow + l15][kt * 32], g);
        const u16* pb = pn2 + (size_t)kt * 4096 + lane * 8;
        #pragma unroll
        for (int nt = 0; nt < 8; ++nt) {
            s8b b = *(const s8b*)(pb + nt * 512);
            acc2[nt] = mfma16(a, b, acc2[nt]);
        }
    }
    {
        const float* b2 = nb2 + (size_t)layer * DD;
        #pragma unroll
        for (int nt = 0; nt < 8; ++nt) {
            int n = nt * 16 + l15;
            float bb = b2[n];
            #pragma unroll
            for (int r = 0; r < 4; ++r) {
                int er = wrow + g * 4 + r;
                int node = n0 + er;
                if (node < NND) {
                    float v = acc2[nt][r] + bb + resid[(size_t)node * DD + n];
                    out_h[(size_t)node * DD + n] = v;
                    if (!last) {
                        u16 hv = f2b1(v);
                        hb_out[(size_t)node * DD + n] = hv;
                        tH[er][n] = hv;           // stage h_{l+1} for P/Q GEMM
                    }
                } else if (!last) {
                    tH[er][n] = 0;
                }
            }
        }
    }

    if (!last) {
        __syncthreads();
        // next-layer P = h@W1a + b1 (f32), Q = h@W1b (bf16)
        f4 accP[8], accQ[8];
        #pragma unroll
        for (int nt = 0; nt < 8; ++nt) { accP[nt] = f4{0.f,0.f,0.f,0.f}; accQ[nt] = f4{0.f,0.f,0.f,0.f}; }
        const u16* pwa = pw + (size_t)((layer + 1) * 6 + 0) * 16384;
        const u16* pwb = pw + (size_t)((layer + 1) * 6 + 1) * 16384;
        #pragma unroll
        for (int kt = 0; kt < 4; ++kt) {
            s8b a = frag_a(&tH[wrow + l15][kt * 32], g);
            const u16* ba = pwa + (size_t)kt * 4096 + lane * 8;
            const u16* bb = pwb + (size_t)kt * 4096 + lane * 8;
            #pragma unroll
            for (int nt = 0; nt < 8; ++nt) {
                accP[nt] = mfma16(a, *(const s8b*)(ba + nt * 512), accP[nt]);
                accQ[nt] = mfma16(a, *(const s8b*)(bb + nt * 512), accQ[nt]);
            }
        }
        #pragma unroll
        for (int nt = 0; nt < 8; ++nt) {
            int n = nt * 16 + l15;
            float bb = eb1[(size_t)(layer + 1) * DD + n];
            #pragma unroll
            for (int r = 0; r < 4; ++r) {
                int node = n0 + wrow + g * 4 + r;
                if (node < NND) {
                    Pb[(size_t)node * DD + n] = accP[nt][r] + bb;
                    Qb[(size_t)node * DD + n] = f2b1(accQ[nt][r]);
                }
            }
        }
    }
}

// ---------------- final coord output ----------------
__global__ __launch_bounds__(256) void egnn_coord_out(
    const float* __restrict__ xin, const float* __restrict__ aggx,
    const int* __restrict__ off, float* __restrict__ out_x)
{
    int i = blockIdx.x * 256 + threadIdx.x;
    if (i >= NND) return;
    float c = (float)(off[i + 1] - off[i]);
    float inv = 1.0f / fmaxf(c, 1.0f);
    out_x[i * 3 + 0] = xin[i * 3 + 0] + aggx[i * 3 + 0] * inv;
    out_x[i * 3 + 1] = xin[i * 3 + 1] + aggx[i * 3 + 1] * inv;
    out_x[i * 3 + 2] = xin[i * 3 + 2] + aggx[i * 3 + 2] * inv;
}

extern "C" void kernel_launch(void* const* d_in, const int* in_sizes, int n_in,
                              void* d_out, int out_size, void* d_ws, size_t ws_size,
                              hipStream_t stream) {
    const float* h   = (const float*)d_in[0];
    const float* x   = (const float*)d_in[1];
    const int*  edges= (const int*)d_in[2];
    const float* ew1 = (const float*)d_in[3];
    const float* eb1 = (const float*)d_in[4];
    const float* ew2 = (const float*)d_in[5];
    const float* eb2 = (const float*)d_in[6];
    const float* nw1 = (const float*)d_in[7];
    const float* nb1 = (const float*)d_in[8];
    const float* nw2 = (const float*)d_in[9];
    const float* nb2 = (const float*)d_in[10];
    const float* cw1 = (const float*)d_in[11];
    const float* cb1 = (const float*)d_in[12];
    const float* cw2 = (const float*)d_in[13];

    char* ws = (char*)d_ws;
    u16*   hb   = (u16*)  (ws);                    //  2,560,000
    u16*   pw   = (u16*)  (ws + 2560000);          //    819,200
    int*   cnts = (int*)  (ws + 3379200);          //     40,016
    int*   off  = (int*)  (ws + 3419216);          //     40,016
    int*   curs = (int*)  (ws + 3459232);          //     40,016
    int*   rows = (int*)  (ws + 3499248);          //  1,280,000
    int*   cols = (int*)  (ws + 4779248);          //  1,280,000
    float* aggx = (float*)(ws + 6059248);          //    120,064
    float* Pb   = (float*)(ws + 6179312);          //  5,120,000
    u16*   Qb   = (u16*)  (ws + 11299312);         //  2,560,000
    float* magg = (float*)(ws + 13859312);         //  5,120,000  (total 18,979,312)

    float* out_h = (float*)d_out;
    float* out_x = out_h + (size_t)NND * DD;

    egnn_pack<<<1600, 256, 0, stream>>>(ew1, ew2, nw1, nw2, cw1, pw);
    egnn_init<<<1250, 256, 0, stream>>>(h, hb);
    hipMemsetAsync(aggx, 0, 120064, stream);
    hipMemsetAsync(cnts, 0, 40016, stream);

    egnn_count<<<1250, 256, 0, stream>>>(edges, cnts);
    egnn_scan<<<1, 1024, 0, stream>>>(cnts, off, curs);
    egnn_scatter<<<1250, 256, 0, stream>>>(edges, curs, rows, cols);
    egnn_pre0<<<(NND + 63) / 64, 256, 0, stream>>>(hb, pw, eb1, Pb, Qb);

    for (int i = 0; i < NDEPTH; ++i) {
        int last = (i == NDEPTH - 1);
        hipMemsetAsync(magg, 0, (size_t)NND * DD * 4, stream);
        egnn_edge<<<NE / TE, 256, 0, stream>>>(Pb, Qb, x, rows, cols, off, pw,
                                               ew1, eb2, cb1, cw2,
                                               magg, aggx, i, last);
        const float* resid = (i == 0) ? h : (const float*)out_h;
        egnn_node<<<(NND + 63) / 64, 256, 0, stream>>>(hb, resid, magg, pw, nb1, nb2, eb1,
                                                       out_h, hb, Pb, Qb, i, last);
    }
    egnn_coord_out<<<40, 256, 0, stream>>>(x, aggx, off, out_x);
}

// Round 12
// 476.804 us; speedup vs baseline: 1.9456x; 1.0713x over previous
//
#include <hip/hip_runtime.h>

#define NND 10000
#define NE  320000
#define DD  128
#define NDEPTH 4
#define TE  64   // edges per block in edge kernel (256 threads, 4 waves, 16 rows/wave)
#define NSLOT 4  // partial-sum slots per node (safe to degree 192)

typedef __attribute__((ext_vector_type(8))) short s8b;
typedef __attribute__((ext_vector_type(4))) float f4;
typedef unsigned short u16;
typedef unsigned int   u32;

__device__ __forceinline__ u16 f2b(float f) {
    u32 u = __builtin_bit_cast(u32, f);
    u32 r = (u + 0x7fffu + ((u >> 16) & 1u)) >> 16;   // RNE, finite inputs
    return (u16)r;
}

__device__ __forceinline__ float b2f(u16 b) {
    u32 u = (u32)b << 16;
    return __builtin_bit_cast(float, u);
}

__device__ __forceinline__ void bpair(u32 v, float& lo, float& hi) {
    lo = __builtin_bit_cast(float, v << 16);
    hi = __builtin_bit_cast(float, v & 0xffff0000u);
}

// packed RNE f32x2 -> bf16x2 (lo = first arg)
__device__ __forceinline__ u32 cvt_pk(float lo, float hi) {
    u32 r;
    asm("v_cvt_pk_bf16_f32 %0, %1, %2" : "=v"(r) : "v"(lo), "v"(hi));
    return r;
}

// single f32 -> bf16 via HW cvt (1 instruction vs 5-op manual RNE)
__device__ __forceinline__ u16 f2b1(float v) {
    return (u16)cvt_pk(v, v);
}

// fast silu: v * rcp(1+exp(-v)); output always rounds to bf16 downstream,
// so v_rcp_f32's ~1ulp is invisible.
__device__ __forceinline__ float silu_f(float v) {
    return v * __builtin_amdgcn_rcpf(1.0f + __expf(-v));
}

// A-fragment for mfma_f32_16x16x32_bf16: lane holds k = k0 + {4g..4g+3, 16+4g..16+4g+3}
__device__ __forceinline__ s8b frag_a(const u16* rowp, int g) {
    union { s8b v; uint2 u2[2]; } r;
    r.u2[0] = *(const uint2*)(rowp + 4 * g);
    r.u2[1] = *(const uint2*)(rowp + 16 + 4 * g);
    return r.v;
}

__device__ __forceinline__ f4 mfma16(s8b a, s8b b, f4 c) {
    return __builtin_amdgcn_mfma_f32_16x16x32_bf16(a, b, c, 0, 0, 0);
}

// ---------------- weight packing: B-fragment layout, bf16 ----------------
__global__ __launch_bounds__(256) void egnn_pack(
    const float* __restrict__ ew1, const float* __restrict__ ew2,
    const float* __restrict__ nw1, const float* __restrict__ nw2,
    const float* __restrict__ cw1, u16* __restrict__ pw)
{
    int t = blockIdx.x * 256 + threadIdx.x;
    if (t >= 25 * 16384) return;
    int mat = t >> 14;
    int r   = t & 16383;
    int kt  = r >> 12;
    int nt  = (r >> 9) & 7;
    int lane= (r >> 3) & 63;
    int j   = r & 7;
    int g = lane >> 4, l15 = lane & 15;
    int k = kt * 32 + ((j < 4) ? (4 * g + j) : (16 + 4 * g + (j - 4)));
    int n = nt * 16 + l15;
    float v;
    if (mat < 24) {
        int layer = mat / 6, tp = mat % 6;
        switch (tp) {
            case 0: v = ew1[((size_t)layer * 257 + k) * DD + n]; break;
            case 1: v = ew1[((size_t)layer * 257 + 128 + k) * DD + n]; break;
            case 2: v = ew2[((size_t)layer * 128 + k) * DD + n]; break;
            case 3: v = nw1[((size_t)layer * 256 + k) * DD + n]; break;
            case 4: v = nw1[((size_t)layer * 256 + 128 + k) * DD + n]; break;
            default: v = nw2[((size_t)layer * 128 + k) * DD + n]; break;
        }
    } else {
        v = cw1[(size_t)k * DD + n];
    }
    pw[t] = f2b(v);
}

// ---------------- h init: bf16 copy ----------------
__global__ __launch_bounds__(256) void egnn_init(
    const float* __restrict__ h, u16* __restrict__ hb)
{
    int i = blockIdx.x * 256 + threadIdx.x;
    size_t base = (size_t)i * 4;
    if (base >= (size_t)NND * DD) return;
    float4 v = *(const float4*)(h + base);
    union { u16 s[4]; uint2 u; } t2;
    t2.s[0] = f2b(v.x); t2.s[1] = f2b(v.y); t2.s[2] = f2b(v.z); t2.s[3] = f2b(v.w);
    *(uint2*)(hb + base) = t2.u;
}

// ---------------- counting sort by row ----------------
__global__ __launch_bounds__(256) void egnn_count(
    const int* __restrict__ edges, int* __restrict__ cnts)
{
    int e = blockIdx.x * 256 + threadIdx.x;
    if (e < NE) atomicAdd(&cnts[edges[e]], 1);
}

__global__ __launch_bounds__(1024) void egnn_scan(
    const int* __restrict__ cnts, int* __restrict__ off, int* __restrict__ cursor)
{
    __shared__ int part[1024];
    const int t = threadIdx.x;
    const int base = t * 10;
    int s = 0;
    #pragma unroll
    for (int j = 0; j < 10; ++j) {
        int i = base + j;
        s += (i < NND) ? cnts[i] : 0;
    }
    part[t] = s;
    __syncthreads();
    for (int d = 1; d < 1024; d <<= 1) {
        int v = (t >= d) ? part[t - d] : 0;
        __syncthreads();
        part[t] += v;
        __syncthreads();
    }
    int run = (t == 0) ? 0 : part[t - 1];
    #pragma unroll
    for (int j = 0; j < 10; ++j) {
        int i = base + j;
        if (i <= NND) { off[i] = run; cursor[i] = run; }
        if (i < NND) run += cnts[i];
    }
}

// writes row-sorted (rows, cols) pair; no perm indirection needed later
__global__ __launch_bounds__(256) void egnn_scatter(
    const int* __restrict__ edges, int* __restrict__ cursor,
    int* __restrict__ rows, int* __restrict__ cols)
{
    int e = blockIdx.x * 256 + threadIdx.x;
    if (e >= NE) return;
    int r = edges[e];
    int p = atomicAdd(&cursor[r], 1);
    rows[p] = r;
    cols[p] = edges[NE + e];
}

// ---------------- layer-0 P/Q precompute: P=h@W1a+b1 (f32), Q=h@W1b (bf16) ----------------
__global__ __launch_bounds__(256) void egnn_pre0(
    const u16* __restrict__ hb, const u16* __restrict__ pw,
    const float* __restrict__ eb1,
    float* __restrict__ Pb, u16* __restrict__ Qb)
{
    __shared__ __attribute__((aligned(16))) u16 tH[64][136];
    const int tid = threadIdx.x;
    const int n0  = blockIdx.x * 64;

    #pragma unroll
    for (int it = 0; it < 4; ++it) {
        int idx = tid + it * 256;            // 0..1023
        int el = idx >> 4, part = idx & 15;
        int node = n0 + el;
        if (node < NND) {
            *(uint4*)&tH[el][part * 8] = *(const uint4*)(hb + (size_t)node * DD + part * 8);
        } else {
            uint4 z = {0u, 0u, 0u, 0u};
            *(uint4*)&tH[el][part * 8] = z;
        }
    }
    __syncthreads();

    const int wv = tid >> 6, lane = tid & 63;
    const int g = lane >> 4, l15 = lane & 15;
    const int wrow = wv * 16;

    f4 accP[8], accQ[8];
    #pragma unroll
    for (int nt = 0; nt < 8; ++nt) { accP[nt] = f4{0.f,0.f,0.f,0.f}; accQ[nt] = f4{0.f,0.f,0.f,0.f}; }
    const u16* pwa = pw;            // layer 0 mat 0 (W1a)
    const u16* pwb = pw + 16384;    // layer 0 mat 1 (W1b)
    #pragma unroll
    for (int kt = 0; kt < 4; ++kt) {
        s8b a = frag_a(&tH[wrow + l15][kt * 32], g);
        const u16* ba = pwa + (size_t)kt * 4096 + lane * 8;
        const u16* bb = pwb + (size_t)kt * 4096 + lane * 8;
        #pragma unroll
        for (int nt = 0; nt < 8; ++nt) {
            accP[nt] = mfma16(a, *(const s8b*)(ba + nt * 512), accP[nt]);
            accQ[nt] = mfma16(a, *(const s8b*)(bb + nt * 512), accQ[nt]);
        }
    }
    #pragma unroll
    for (int nt = 0; nt < 8; ++nt) {
        int n = nt * 16 + l15;
        float bb = eb1[n];      // layer 0 bias folded into P
        #pragma unroll
        for (int r = 0; r < 4; ++r) {
            int node = n0 + wrow + g * 4 + r;
            if (node < NND) {
                Pb[(size_t)node * DD + n] = accP[nt][r] + bb;
                Qb[(size_t)node * DD + n] = f2b1(accQ[nt][r]);
            }
        }
    }
}

// ---------------- edge kernel (sorted edges, tile-partial reduce, ZERO atomics) ----------------
// TE=64, 4 waves, 16 GEMM rows/wave. Q stored bf16 (L2-resident).
// Segmented sums are written as PLAIN stores to private per-(node,tile) slots:
// node rn's range spans tiles off[rn]>>6 .. (off[rn+1]-1)>>6; this block (tile blk)
// owns slot blk-(off[rn]>>6). Single writer per line -> no churn, no memset.
__global__ __launch_bounds__(256, 6) void egnn_edge(
    const float* __restrict__ Pb, const u16* __restrict__ Qb,
    const float* __restrict__ xin,
    const int* __restrict__ rows, const int* __restrict__ cols,
    const int* __restrict__ off,
    const u16* __restrict__ pw,
    const float* __restrict__ ew1,
    const float* __restrict__ eb2, const float* __restrict__ cb1,
    const float* __restrict__ cw2,
    float* __restrict__ part, float* __restrict__ aggx,
    int layer, int last)
{
    __shared__ __attribute__((aligned(16))) u16 tA[TE][136];  // m1 then m2 (in-place)
    __shared__ float rad[TE];
    __shared__ float cdf[TE][3];
    __shared__ int   ridx[TE];
    __shared__ int   cidx[TE];
    __shared__ unsigned char segflag[TE + 1];

    const int tid = threadIdx.x;
    // bijective XCD swizzle (grid 5000 % 8 == 0)
    const int nblk = NE / TE;
    const int bid  = blockIdx.x;
    const int blk  = (bid & 7) * (nblk >> 3) + (bid >> 3);
    const int p0   = blk * TE;

    if (tid < TE) {
        int p = p0 + tid;
        int r = rows[p];
        int c = cols[p];
        ridx[tid] = r; cidx[tid] = c;
        float d0 = xin[r * 3 + 0] - xin[c * 3 + 0];
        float d1 = xin[r * 3 + 1] - xin[c * 3 + 1];
        float d2 = xin[r * 3 + 2] - xin[c * 3 + 2];
        rad[tid] = d0 * d0 + d1 * d1 + d2 * d2;
        cdf[tid][0] = d0; cdf[tid][1] = d1; cdf[tid][2] = d2;
    }
    __syncthreads();

    if (tid < TE) {
        segflag[tid] = (tid == 0) || (ridx[tid] != ridx[tid - 1]);
        if (tid == 0) segflag[TE] = 1;
    }

    // ---- staging: m1 = silu(P'[row] + Q[col] + rad*w1r) -> tA (bf16)
    {
        const int cg = tid & 15;        // cols cg*8 .. cg*8+7
        const int rg = tid >> 4;        // 0..15, rows rg + 16*k
        const float* wrp = ew1 + ((size_t)layer * 257 + 256) * DD + cg * 8;
        float4 w0 = *(const float4*)(wrp);
        float4 w4 = *(const float4*)(wrp + 4);
        #pragma unroll
        for (int k = 0; k < 4; ++k) {
            int row = rg + 16 * k;
            int rn = ridx[row], cn = cidx[row];
            float rd = rad[row];
            const float* pp = Pb + (size_t)rn * DD + cg * 8;
            float4 pa = *(const float4*)(pp);
            float4 pc = *(const float4*)(pp + 4);
            uint4 qv = *(const uint4*)(Qb + (size_t)cn * DD + cg * 8);
            float q0, q1, q2, q3, q4, q5, q6, q7;
            bpair(qv.x, q0, q1);
            bpair(qv.y, q2, q3);
            bpair(qv.z, q4, q5);
            bpair(qv.w, q6, q7);
            float v0 = silu_f(pa.x + q0 + rd * w0.x);
            float v1 = silu_f(pa.y + q1 + rd * w0.y);
            float v2 = silu_f(pa.z + q2 + rd * w0.z);
            float v3 = silu_f(pa.w + q3 + rd * w0.w);
            float v4 = silu_f(pc.x + q4 + rd * w4.x);
            float v5 = silu_f(pc.y + q5 + rd * w4.y);
            float v6 = silu_f(pc.z + q6 + rd * w4.z);
            float v7 = silu_f(pc.w + q7 + rd * w4.w);
            union { u32 w[4]; uint4 u; } cv;
            cv.w[0] = cvt_pk(v0, v1);
            cv.w[1] = cvt_pk(v2, v3);
            cv.w[2] = cvt_pk(v4, v5);
            cv.w[3] = cvt_pk(v6, v7);
            *(uint4*)&tA[row][cg * 8] = cv.u;
        }
    }
    __syncthreads();

    const int wv = tid >> 6, lane = tid & 63;
    const int g = lane >> 4, l15 = lane & 15;
    const int wrow = wv * 16;

    // ---- GEMM2: m1 (K=128) @ W2, 16 rows per wave
    f4 acc2[8];
    #pragma unroll
    for (int nt = 0; nt < 8; ++nt) acc2[nt] = f4{0.f, 0.f, 0.f, 0.f};
    const u16* pw2 = pw + (size_t)(layer * 6 + 2) * 16384;
    #pragma unroll
    for (int kt = 0; kt < 4; ++kt) {
        s8b a = frag_a(&tA[wrow + l15][kt * 32], g);
        const u16* pb = pw2 + (size_t)kt * 4096 + lane * 8;
        #pragma unroll
        for (int nt = 0; nt < 8; ++nt) {
            s8b b = *(const s8b*)(pb + nt * 512);
            acc2[nt] = mfma16(a, b, acc2[nt]);
        }
    }
    // epilogue: m2 = silu(acc2 + b2) -> tA in place (wave-private rows)
    {
        const float* b2 = eb2 + (size_t)layer * DD;
        #pragma unroll
        for (int nt = 0; nt < 8; ++nt) {
            int n = nt * 16 + l15;
            float bb = b2[n];
            #pragma unroll
            for (int r = 0; r < 4; ++r) {
                int er = wrow + g * 4 + r;
                float v = silu_f(acc2[nt][r] + bb);
                tA[er][n] = f2b1(v);
            }
        }
    }
    __syncthreads();

    // ---- segmented reduce -> private partial slots (plain stores, no atomics)
    if (tid < 128) {
        int col = tid;
        float s = 0.f;
        for (int row = 0; row < TE; ++row) {
            s += b2f(tA[row][col]);
            if (segflag[row + 1] || row == TE - 1) {
                int rn = ridx[row];
                int slot = blk - (off[rn] >> 6);     // 0..NSLOT-1 (single writer)
                part[((size_t)rn * NSLOT + slot) * DD + col] = s;
                s = 0.f;
            }
        }
    }

    if (last) {
        // ---- coord GEMM: m2 (K=128) @ Wc1 ; dot with cw2 ; aggregate trans
        f4 acc3[8];
        #pragma unroll
        for (int nt = 0; nt < 8; ++nt) acc3[nt] = f4{0.f, 0.f, 0.f, 0.f};
        const u16* pwc = pw + (size_t)24 * 16384;
        #pragma unroll
        for (int kt = 0; kt < 4; ++kt) {
            s8b a = frag_a(&tA[wrow + l15][kt * 32], g);
            const u16* pb = pwc + (size_t)kt * 4096 + lane * 8;
            #pragma unroll
            for (int nt = 0; nt < 8; ++nt) {
                s8b b = *(const s8b*)(pb + nt * 512);
                acc3[nt] = mfma16(a, b, acc3[nt]);
            }
        }
        float p[4];
        #pragma unroll
        for (int r = 0; r < 4; ++r) p[r] = 0.f;
        #pragma unroll
        for (int nt = 0; nt < 8; ++nt) {
            int n = nt * 16 + l15;
            float bb = cb1[n], w2 = cw2[n];
            #pragma unroll
            for (int r = 0; r < 4; ++r)
                p[r] += silu_f(acc3[nt][r] + bb) * w2;
        }
        #pragma unroll
        for (int o = 1; o < 16; o <<= 1) {
            #pragma unroll
            for (int r = 0; r < 4; ++r)
                p[r] += __shfl_xor(p[r], o);
        }
        if (l15 == 0) {
            #pragma unroll
            for (int r = 0; r < 4; ++r) {
                int er = wrow + 4 * g + r;
                int rn2 = ridx[er];
                float w = p[r];
                atomicAdd(&aggx[rn2 * 3 + 0], cdf[er][0] * w);
                atomicAdd(&aggx[rn2 * 3 + 1], cdf[er][1] * w);
                atomicAdd(&aggx[rn2 * 3 + 2], cdf[er][2] * w);
            }
        }
    }
}

// ---------------- node kernel (+ fused next-layer P/Q precompute) ----------------
// tM staged by summing the node's 1..NSLOT tile-partials (no magg buffer at all)
__global__ __launch_bounds__(256) void egnn_node(
    const u16* __restrict__ hb, const float* __restrict__ resid,
    const float* __restrict__ part, const int* __restrict__ off,
    const u16* __restrict__ pw,
    const float* __restrict__ nb1, const float* __restrict__ nb2,
    const float* __restrict__ eb1,
    float* __restrict__ out_h, u16* __restrict__ hb_out,
    float* __restrict__ Pb, u16* __restrict__ Qb,
    int layer, int last)
{
    __shared__ __attribute__((aligned(16))) u16 tH[64][136];
    __shared__ __attribute__((aligned(16))) u16 tM[64][136];
    const int tid = threadIdx.x;
    const int n0  = blockIdx.x * 64;

    #pragma unroll
    for (int it = 0; it < 4; ++it) {
        int idx = tid + it * 256;            // 0..1023
        int el = idx >> 4, pt = idx & 15;
        int node = n0 + el;
        if (node < NND) {
            *(uint4*)&tH[el][pt * 8] = *(const uint4*)(hb + (size_t)node * DD + pt * 8);
            // sum tile-partials for this node (contiguous slots, 1..NSLOT live)
            float4 s0 = float4{0.f, 0.f, 0.f, 0.f};
            float4 s1 = float4{0.f, 0.f, 0.f, 0.f};
            int a = off[node], b = off[node + 1];
            if (a < b) {
                int nsl = ((b - 1) >> 6) - (a >> 6) + 1;
                const float* pp = part + (size_t)node * NSLOT * DD + pt * 8;
                for (int t = 0; t < nsl; ++t) {
                    float4 v0 = *(const float4*)(pp);
                    float4 v1 = *(const float4*)(pp + 4);
                    s0.x += v0.x; s0.y += v0.y; s0.z += v0.z; s0.w += v0.w;
                    s1.x += v1.x; s1.y += v1.y; s1.z += v1.z; s1.w += v1.w;
                    pp += DD;
                }
            }
            union { u32 w[4]; uint4 u; } cv;
            cv.w[0] = cvt_pk(s0.x, s0.y);
            cv.w[1] = cvt_pk(s0.z, s0.w);
            cv.w[2] = cvt_pk(s1.x, s1.y);
            cv.w[3] = cvt_pk(s1.z, s1.w);
            *(uint4*)&tM[el][pt * 8] = cv.u;
        } else {
            uint4 z = {0u, 0u, 0u, 0u};
            *(uint4*)&tH[el][pt * 8] = z;
            *(uint4*)&tM[el][pt * 8] = z;
        }
    }
    __syncthreads();

    const int wv = tid >> 6, lane = tid & 63;
    const int g = lane >> 4, l15 = lane & 15;
    const int wrow = wv * 16;

    f4 acc[8];
    #pragma unroll
    for (int nt = 0; nt < 8; ++nt) acc[nt] = f4{0.f, 0.f, 0.f, 0.f};
    const u16* pn1a = pw + (size_t)(layer * 6 + 3) * 16384;
    const u16* pn1b = pw + (size_t)(layer * 6 + 4) * 16384;
    #pragma unroll
    for (int kt = 0; kt < 8; ++kt) {
        const u16 (*tile)[136] = (kt < 4) ? tH : tM;
        const int k0 = (kt & 3) * 32;
        s8b a = frag_a(&tile[wrow + l15][k0], g);
        const u16* pb = ((kt < 4) ? pn1a : pn1b) + (size_t)(kt & 3) * 4096 + lane * 8;
        #pragma unroll
        for (int nt = 0; nt < 8; ++nt) {
            s8b b = *(const s8b*)(pb + nt * 512);
            acc[nt] = mfma16(a, b, acc[nt]);
        }
    }
    {
        const float* b1 = nb1 + (size_t)layer * DD;
        #pragma unroll
        for (int nt = 0; nt < 8; ++nt) {
            int n = nt * 16 + l15;
            float bb = b1[n];
            #pragma unroll
            for (int r = 0; r < 4; ++r) {
                int er = wrow + g * 4 + r;
                tM[er][n] = f2b1(silu_f(acc[nt][r] + bb));
            }
        }
    }
    __syncthreads();

    f4 acc2[8];
    #pragma unroll
    for (int nt = 0; nt < 8; ++nt) acc2[nt] = f4{0.f, 0.f, 0.f, 0.f};
    const u16* pn2 = pw + (size_t)(layer * 6 + 5) * 16384;
    #pragma unroll
    for (int kt = 0; kt < 4; ++kt) {
        s8b a = frag_a(&tM[wrow + l15][kt * 32], g);
        const u16* pb = pn2 + (size_t)kt * 4096 + lane * 8;
        #pragma unroll
        for (int nt = 0; nt < 8; ++nt) {
            s8b b = *(const s8b*)(pb + nt * 512);
            acc2[nt] = mfma16(a, b, acc2[nt]);
        }
    }
    {
        const float* b2 = nb2 + (size_t)layer * DD;
        #pragma unroll
        for (int nt = 0; nt < 8; ++nt) {
            int n = nt * 16 + l15;
            float bb = b2[n];
            #pragma unroll
            for (int r = 0; r < 4; ++r) {
                int er = wrow + g * 4 + r;
                int node = n0 + er;
                if (node < NND) {
                    float v = acc2[nt][r] + bb + resid[(size_t)node * DD + n];
                    out_h[(size_t)node * DD + n] = v;
                    if (!last) {
                        u16 hv = f2b1(v);
                        hb_out[(size_t)node * DD + n] = hv;
                        tH[er][n] = hv;           // stage h_{l+1} for P/Q GEMM
                    }
                } else if (!last) {
                    tH[er][n] = 0;
                }
            }
        }
    }

    if (!last) {
        __syncthreads();
        // next-layer P = h@W1a + b1 (f32), Q = h@W1b (bf16)
        f4 accP[8], accQ[8];
        #pragma unroll
        for (int nt = 0; nt < 8; ++nt) { accP[nt] = f4{0.f,0.f,0.f,0.f}; accQ[nt] = f4{0.f,0.f,0.f,0.f}; }
        const u16* pwa = pw + (size_t)((layer + 1) * 6 + 0) * 16384;
        const u16* pwb = pw + (size_t)((layer + 1) * 6 + 1) * 16384;
        #pragma unroll
        for (int kt = 0; kt < 4; ++kt) {
            s8b a = frag_a(&tH[wrow + l15][kt * 32], g);
            const u16* ba = pwa + (size_t)kt * 4096 + lane * 8;
            const u16* bb = pwb + (size_t)kt * 4096 + lane * 8;
            #pragma unroll
            for (int nt = 0; nt < 8; ++nt) {
                accP[nt] = mfma16(a, *(const s8b*)(ba + nt * 512), accP[nt]);
                accQ[nt] = mfma16(a, *(const s8b*)(bb + nt * 512), accQ[nt]);
            }
        }
        #pragma unroll
        for (int nt = 0; nt < 8; ++nt) {
            int n = nt * 16 + l15;
            float bb = eb1[(size_t)(layer + 1) * DD + n];
            #pragma unroll
            for (int r = 0; r < 4; ++r) {
                int node = n0 + wrow + g * 4 + r;
                if (node < NND) {
                    Pb[(size_t)node * DD + n] = accP[nt][r] + bb;
                    Qb[(size_t)node * DD + n] = f2b1(accQ[nt][r]);
                }
            }
        }
    }
}

// ---------------- final coord output ----------------
__global__ __launch_bounds__(256) void egnn_coord_out(
    const float* __restrict__ xin, const float* __restrict__ aggx,
    const int* __restrict__ off, float* __restrict__ out_x)
{
    int i = blockIdx.x * 256 + threadIdx.x;
    if (i >= NND) return;
    float c = (float)(off[i + 1] - off[i]);
    float inv = 1.0f / fmaxf(c, 1.0f);
    out_x[i * 3 + 0] = xin[i * 3 + 0] + aggx[i * 3 + 0] * inv;
    out_x[i * 3 + 1] = xin[i * 3 + 1] + aggx[i * 3 + 1] * inv;
    out_x[i * 3 + 2] = xin[i * 3 + 2] + aggx[i * 3 + 2] * inv;
}

extern "C" void kernel_launch(void* const* d_in, const int* in_sizes, int n_in,
                              void* d_out, int out_size, void* d_ws, size_t ws_size,
                              hipStream_t stream) {
    const float* h   = (const float*)d_in[0];
    const float* x   = (const float*)d_in[1];
    const int*  edges= (const int*)d_in[2];
    const float* ew1 = (const float*)d_in[3];
    const float* eb1 = (const float*)d_in[4];
    const float* ew2 = (const float*)d_in[5];
    const float* eb2 = (const float*)d_in[6];
    const float* nw1 = (const float*)d_in[7];
    const float* nb1 = (const float*)d_in[8];
    const float* nw2 = (const float*)d_in[9];
    const float* nb2 = (const float*)d_in[10];
    const float* cw1 = (const float*)d_in[11];
    const float* cb1 = (const float*)d_in[12];
    const float* cw2 = (const float*)d_in[13];

    char* ws = (char*)d_ws;
    u16*   hb   = (u16*)  (ws);                    //  2,560,000
    u16*   pw   = (u16*)  (ws + 2560000);          //    819,200
    int*   cnts = (int*)  (ws + 3379200);          //     40,016
    int*   off  = (int*)  (ws + 3419216);          //     40,016
    int*   curs = (int*)  (ws + 3459232);          //     40,016
    int*   rows = (int*)  (ws + 3499248);          //  1,280,000
    int*   cols = (int*)  (ws + 4779248);          //  1,280,000
    float* aggx = (float*)(ws + 6059248);          //    120,064
    float* Pb   = (float*)(ws + 6179312);          //  5,120,000
    u16*   Qb   = (u16*)  (ws + 11299312);         //  2,560,000
    float* part = (float*)(ws + 13859312);         // 20,480,000  (total 34,339,312)

    float* out_h = (float*)d_out;
    float* out_x = out_h + (size_t)NND * DD;

    egnn_pack<<<1600, 256, 0, stream>>>(ew1, ew2, nw1, nw2, cw1, pw);
    egnn_init<<<1250, 256, 0, stream>>>(h, hb);
    hipMemsetAsync(aggx, 0, 120064, stream);
    hipMemsetAsync(cnts, 0, 40016, stream);

    egnn_count<<<1250, 256, 0, stream>>>(edges, cnts);
    egnn_scan<<<1, 1024, 0, stream>>>(cnts, off, curs);
    egnn_scatter<<<1250, 256, 0, stream>>>(edges, curs, rows, cols);
    egnn_pre0<<<(NND + 63) / 64, 256, 0, stream>>>(hb, pw, eb1, Pb, Qb);

    for (int i = 0; i < NDEPTH; ++i) {
        int last = (i == NDEPTH - 1);
        egnn_edge<<<NE / TE, 256, 0, stream>>>(Pb, Qb, x, rows, cols, off, pw,
                                               ew1, eb2, cb1, cw2,
                                               part, aggx, i, last);
        const float* resid = (i == 0) ? h : (const float*)out_h;
        egnn_node<<<(NND + 63) / 64, 256, 0, stream>>>(hb, resid, part, off,
                                                       pw, nb1, nb2, eb1,
                                                       out_h, hb, Pb, Qb, i, last);
    }
    egnn_coord_out<<<40, 256, 0, stream>>>(x, aggx, off, out_x);
}